// Round 1
// baseline (2555.238 us; speedup 1.0000x reference)
//
#include <hip/hip_runtime.h>
#include <math.h>

#define NUM_LAYERS 3
#define KCB 2048        // codebook size
#define DIM 256         // embed dim
#define NROWS 32768     // B*T
#define MROWS 32        // rows per block
#define KC 256          // codeword chunk
#define DC 32           // d chunk staged per pass
#define RSTRIDE 260     // 256 + 4 pad
#define WSTRIDE 36      // 32 + 4 pad
#define NQ (NROWS * DIM)

__global__ __launch_bounds__(256, 2)
void rvq_fused(const float* __restrict__ h,
               const float* __restrict__ cb,
               float* __restrict__ out)
{
    __shared__ __align__(16) float Rsh[MROWS][RSTRIDE];
    __shared__ __align__(16) float Wsh[KC][WSTRIDE];
    __shared__ float wsq_sh[KC];
    __shared__ float rsq_sh[MROWS];
    __shared__ int   bidx_sh[MROWS];

    const int t    = threadIdx.x;
    const int cg   = t & 31;   // codeword group 0..31
    const int rg   = t >> 5;   // row group 0..7 (4 rows each)
    const int row0 = blockIdx.x * MROWS;

    // ---- Stage residual = h tile (coalesced float4) ----
    #pragma unroll
    for (int p = 0; p < 8; ++p) {
        int q = p * 256 + t;
        int row = q >> 6;
        int fid = q & 63;
        const float4 v = *(const float4*)(h + (size_t)(row0 + row) * DIM + fid * 4);
        *(float4*)(&Rsh[row][fid * 4]) = v;
    }
    __syncthreads();

    for (int l = 0; l < NUM_LAYERS; ++l) {
        const float* __restrict__ W = cb + (size_t)l * KCB * DIM;

        // ---- per-row ||r||^2 (8 lanes per row, shuffle-reduce) ----
        {
            int row = t >> 3, g = t & 7;
            float s = 0.f;
            #pragma unroll
            for (int u = 0; u < 8; ++u) {
                float4 v = *(const float4*)(&Rsh[row][g * 32 + u * 4]);
                s = fmaf(v.x, v.x, s); s = fmaf(v.y, v.y, s);
                s = fmaf(v.z, v.z, s); s = fmaf(v.w, v.w, s);
            }
            s += __shfl_xor(s, 4, 8);
            s += __shfl_xor(s, 2, 8);
            s += __shfl_xor(s, 1, 8);
            if (g == 0) rsq_sh[row] = s;
        }
        __syncthreads();

        float rsq[4];
        #pragma unroll
        for (int i = 0; i < 4; ++i) rsq[i] = rsq_sh[rg * 4 + i];

        float bestV[4];
        int   bestI[4];
        #pragma unroll
        for (int i = 0; i < 4; ++i) { bestV[i] = INFINITY; bestI[i] = 0; }

        for (int kb = 0; kb < KCB; kb += KC) {
            __syncthreads();          // previous chunk's wsq_sh reads done
            wsq_sh[t] = 0.f;          // t covers exactly KC=256

            float acc[4][8];
            #pragma unroll
            for (int i = 0; i < 4; ++i)
                #pragma unroll
                for (int j = 0; j < 8; ++j) acc[i][j] = 0.f;

            for (int db = 0; db < DIM; db += DC) {
                __syncthreads();      // Wsh overwrite hazard; orders wsq zeroing
                // ---- stage W chunk [256 cw x 32 d], accumulate ||w||^2 ----
                #pragma unroll
                for (int p = 0; p < 8; ++p) {
                    int q = p * 256 + t;
                    int c = q >> 3;
                    int fid = q & 7;
                    const float4 v = *(const float4*)(W + (size_t)(kb + c) * DIM + db + fid * 4);
                    *(float4*)(&Wsh[c][fid * 4]) = v;
                    float ps = fmaf(v.x, v.x, fmaf(v.y, v.y, fmaf(v.z, v.z, v.w * v.w)));
                    ps += __shfl_xor(ps, 4, 8);
                    ps += __shfl_xor(ps, 2, 8);
                    ps += __shfl_xor(ps, 1, 8);
                    if (fid == 0) wsq_sh[c] += ps;
                }
                __syncthreads();
                // ---- inner product: 4 rows x 8 cw per thread ----
                #pragma unroll
                for (int dd = 0; dd < DC; dd += 4) {
                    float4 rf[4], wf[8];
                    #pragma unroll
                    for (int i = 0; i < 4; ++i)
                        rf[i] = *(const float4*)(&Rsh[rg * 4 + i][db + dd]);
                    #pragma unroll
                    for (int j = 0; j < 8; ++j)
                        wf[j] = *(const float4*)(&Wsh[cg + 32 * j][dd]);
                    #pragma unroll
                    for (int i = 0; i < 4; ++i)
                        #pragma unroll
                        for (int j = 0; j < 8; ++j) {
                            float s = acc[i][j];
                            s = fmaf(rf[i].x, wf[j].x, s);
                            s = fmaf(rf[i].y, wf[j].y, s);
                            s = fmaf(rf[i].z, wf[j].z, s);
                            s = fmaf(rf[i].w, wf[j].w, s);
                            acc[i][j] = s;
                        }
                }
            }
            // ---- chunk epilogue: dist = (r^2 - 2*cross) + w^2, running argmin ----
            #pragma unroll
            for (int j = 0; j < 8; ++j) {
                const int c = kb + cg + 32 * j;
                const float wq = wsq_sh[cg + 32 * j];
                #pragma unroll
                for (int i = 0; i < 4; ++i) {
                    float dist = (rsq[i] - 2.f * acc[i][j]) + wq;
                    if (dist < bestV[i]) { bestV[i] = dist; bestI[i] = c; }
                }
            }
        }

        // ---- reduce argmin across the 32 lanes sharing each row ----
        #pragma unroll
        for (int i = 0; i < 4; ++i) {
            float bv = bestV[i]; int bi = bestI[i];
            #pragma unroll
            for (int s = 16; s; s >>= 1) {
                float ov = __shfl_xor(bv, s, 32);
                int   oi = __shfl_xor(bi, s, 32);
                if (ov < bv || (ov == bv && oi < bi)) { bv = ov; bi = oi; }
            }
            if (cg == 0) {
                bidx_sh[rg * 4 + i] = bi;
                out[NQ + (size_t)l * NROWS + row0 + rg * 4 + i] = (float)bi;
            }
        }
        __syncthreads();

        // ---- residual -= chosen codeword (gather from L2) ----
        #pragma unroll
        for (int p = 0; p < 8; ++p) {
            int q = p * 256 + t;
            int row = q >> 6;
            int fid = q & 63;
            const int bi = bidx_sh[row];
            const float4 w = *(const float4*)(W + (size_t)bi * DIM + fid * 4);
            float4 r = *(float4*)(&Rsh[row][fid * 4]);
            r.x -= w.x; r.y -= w.y; r.z -= w.z; r.w -= w.w;
            *(float4*)(&Rsh[row][fid * 4]) = r;
        }
        __syncthreads();
    }

    // ---- quantized_total = h - final residual ----
    #pragma unroll
    for (int p = 0; p < 8; ++p) {
        int q = p * 256 + t;
        int row = q >> 6;
        int fid = q & 63;
        const float4 hv = *(const float4*)(h + (size_t)(row0 + row) * DIM + fid * 4);
        const float4 rv = *(const float4*)(&Rsh[row][fid * 4]);
        float4 o;
        o.x = hv.x - rv.x; o.y = hv.y - rv.y;
        o.z = hv.z - rv.z; o.w = hv.w - rv.w;
        *(float4*)(out + (size_t)(row0 + row) * DIM + fid * 4) = o;
    }
}

extern "C" void kernel_launch(void* const* d_in, const int* in_sizes, int n_in,
                              void* d_out, int out_size, void* d_ws, size_t ws_size,
                              hipStream_t stream) {
    const float* h  = (const float*)d_in[0];
    const float* cb = (const float*)d_in[1];
    float* out = (float*)d_out;
    rvq_fused<<<dim3(NROWS / MROWS), dim3(256), 0, stream>>>(h, cb, out);
}

// Round 2
// 563.132 us; speedup vs baseline: 4.5375x; 4.5375x over previous
//
#include <hip/hip_runtime.h>
#include <math.h>

#define NUM_LAYERS 3
#define KCB 2048        // codebook size
#define DIM 256         // embed dim
#define NROWS 32768     // B*T
#define NQ (NROWS * DIM)
#define RSTRIDE 260     // 256 + 4 pad (16B-aligned rows: 1040 B)

// d_ws layout:
//   F   : fp16 codebook fragments, [(layer*128+tn)*8+kb][s=hi/lo] blocks of 1024 B
//         element: lane*8 + j  ->  W[tn*16 + (lane&15)][kb*32 + (lane>>4)*8 + j]
//   wsq : fp32 ||w||^2 per codeword, 3*2048 floats, at byte offset 6 MiB
#define F_BYTES (3u * 128u * 8u * 2u * 1024u)   // 6,291,456

typedef _Float16 half8 __attribute__((ext_vector_type(8)));
typedef float   f32x4 __attribute__((ext_vector_type(4)));

// ---------------- prep: ||w||^2 ----------------
__global__ void rvq_wsq(const float* __restrict__ cb, float* __restrict__ wsq)
{
    int tid = blockIdx.x * 256 + threadIdx.x;   // 0 .. 6143  (layer*2048 + cw)
    const float* p = cb + (size_t)tid * DIM;
    float s = 0.f;
    #pragma unroll
    for (int u = 0; u < 64; ++u) {
        float4 v = *(const float4*)(p + u * 4);
        s = fmaf(v.x, v.x, s); s = fmaf(v.y, v.y, s);
        s = fmaf(v.z, v.z, s); s = fmaf(v.w, v.w, s);
    }
    wsq[tid] = s;
}

// ---------------- prep: fp16 hi/lo fragment repack ----------------
// grid: 3*128*8 blocks of 64 threads; block b -> (layer, tn, kb)
__global__ void rvq_repack(const float* __restrict__ cb, unsigned short* __restrict__ F)
{
    int b = blockIdx.x;
    int layer = b >> 10;          // /1024
    int rem   = b & 1023;
    int tn    = rem >> 3;
    int kb    = rem & 7;
    int lane  = threadIdx.x;      // 0..63

    int cw = tn * 16 + (lane & 15);
    int k0 = kb * 32 + (lane >> 4) * 8;
    const float* src = cb + ((size_t)(layer * KCB + cw)) * DIM + k0;
    float4 x0 = *(const float4*)(src);
    float4 x1 = *(const float4*)(src + 4);
    float v[8] = {x0.x, x0.y, x0.z, x0.w, x1.x, x1.y, x1.z, x1.w};

    half8 hi, lo;
    #pragma unroll
    for (int j = 0; j < 8; ++j) {
        _Float16 h = (_Float16)v[j];
        hi[j] = h;
        lo[j] = (_Float16)(v[j] - (float)h);
    }
    size_t base = ((size_t)b * 2) * 512;   // ushort units
    *(half8*)(F + base + lane * 8)        = hi;
    *(half8*)(F + base + 512 + lane * 8)  = lo;
}

// ---------------- main fused RVQ ----------------
__global__ __launch_bounds__(256, 2)
void rvq_main(const float* __restrict__ h,
              const float* __restrict__ cb,
              const unsigned short* __restrict__ F,
              const float* __restrict__ wsq,
              float* __restrict__ out)
{
    __shared__ __align__(16) float Rsh[32][RSTRIDE];
    __shared__ float rsq_sh[32];
    __shared__ float bV_sh[4][32];
    __shared__ int   bI_sh[4][32];
    __shared__ int   bidx_sh[32];

    const int t    = threadIdx.x;
    const int lane = t & 63;
    const int wv   = t >> 6;          // wave 0..3 -> codeword quarter
    const int row0 = blockIdx.x * 32;
    const int arow = lane & 15;       // fragment row / C col
    const int aq   = lane >> 4;       // fragment k-quad / C row-quad

    // ---- stage h tile ----
    #pragma unroll
    for (int p = 0; p < 8; ++p) {
        int q = p * 256 + t;
        int row = q >> 6, fid = q & 63;
        *(float4*)(&Rsh[row][fid * 4]) =
            *(const float4*)(h + (size_t)(row0 + row) * DIM + fid * 4);
    }
    __syncthreads();

    for (int l = 0; l < NUM_LAYERS; ++l) {
        const float* __restrict__ W = cb + (size_t)l * KCB * DIM;

        // ---- per-row ||r||^2 ----
        {
            int row = t >> 3, g = t & 7;
            float s = 0.f;
            #pragma unroll
            for (int u = 0; u < 8; ++u) {
                float4 v = *(const float4*)(&Rsh[row][g * 32 + u * 4]);
                s = fmaf(v.x, v.x, s); s = fmaf(v.y, v.y, s);
                s = fmaf(v.z, v.z, s); s = fmaf(v.w, v.w, s);
            }
            s += __shfl_xor(s, 4, 8);
            s += __shfl_xor(s, 2, 8);
            s += __shfl_xor(s, 1, 8);
            if (g == 0) rsq_sh[row] = s;
        }
        __syncthreads();

        // ---- build A fragments (fp16 hi/lo) in registers ----
        half8 ahi[2][8], alo[2][8];
        #pragma unroll
        for (int mi = 0; mi < 2; ++mi)
            #pragma unroll
            for (int kb = 0; kb < 8; ++kb) {
                const float* p = &Rsh[mi * 16 + arow][kb * 32 + aq * 8];
                float4 x0 = *(const float4*)(p);
                float4 x1 = *(const float4*)(p + 4);
                float v[8] = {x0.x, x0.y, x0.z, x0.w, x1.x, x1.y, x1.z, x1.w};
                #pragma unroll
                for (int j = 0; j < 8; ++j) {
                    _Float16 hv = (_Float16)v[j];
                    ahi[mi][kb][j] = hv;
                    alo[mi][kb][j] = (_Float16)(v[j] - (float)hv);
                }
            }

        float rsq[2][4];
        #pragma unroll
        for (int mi = 0; mi < 2; ++mi)
            #pragma unroll
            for (int i = 0; i < 4; ++i)
                rsq[mi][i] = rsq_sh[mi * 16 + aq * 4 + i];

        float bestV[2][4];
        int   bestI[2][4];
        #pragma unroll
        for (int mi = 0; mi < 2; ++mi)
            #pragma unroll
            for (int i = 0; i < 4; ++i) { bestV[mi][i] = INFINITY; bestI[mi][i] = 0; }

        const unsigned short* Fl = F + (size_t)l * 128 * 8 * 2 * 512;
        const float* wql = wsq + l * KCB;

        for (int nt = 0; nt < 32; ++nt) {
            const int tn = wv * 32 + nt;
            const unsigned short* Fb = Fl + (size_t)tn * 8192;  // 8 kb * 2 * 512

            f32x4 acc[2][2] = {};
            #pragma unroll
            for (int kb = 0; kb < 8; ++kb) {
                half8 bhi = *(const half8*)(Fb + (size_t)(kb * 2) * 512 + lane * 8);
                half8 blo = *(const half8*)(Fb + (size_t)(kb * 2 + 1) * 512 + lane * 8);
                const int p = kb & 1;
                acc[0][p] = __builtin_amdgcn_mfma_f32_16x16x32_f16(ahi[0][kb], bhi, acc[0][p], 0, 0, 0);
                acc[1][p] = __builtin_amdgcn_mfma_f32_16x16x32_f16(ahi[1][kb], bhi, acc[1][p], 0, 0, 0);
                acc[0][p] = __builtin_amdgcn_mfma_f32_16x16x32_f16(alo[0][kb], bhi, acc[0][p], 0, 0, 0);
                acc[1][p] = __builtin_amdgcn_mfma_f32_16x16x32_f16(alo[1][kb], bhi, acc[1][p], 0, 0, 0);
                acc[0][p] = __builtin_amdgcn_mfma_f32_16x16x32_f16(ahi[0][kb], blo, acc[0][p], 0, 0, 0);
                acc[1][p] = __builtin_amdgcn_mfma_f32_16x16x32_f16(ahi[1][kb], blo, acc[1][p], 0, 0, 0);
            }
            const int col = wv * 512 + nt * 16 + arow;
            const float wq = wql[col];
            #pragma unroll
            for (int mi = 0; mi < 2; ++mi)
                #pragma unroll
                for (int i = 0; i < 4; ++i) {
                    float c = acc[mi][0][i] + acc[mi][1][i];
                    float dist = (rsq[mi][i] - 2.f * c) + wq;
                    if (dist < bestV[mi][i]) { bestV[mi][i] = dist; bestI[mi][i] = col; }
                }
        }

        // ---- reduce across the 16 lanes sharing each row-quad ----
        #pragma unroll
        for (int mi = 0; mi < 2; ++mi)
            #pragma unroll
            for (int i = 0; i < 4; ++i) {
                float bv = bestV[mi][i]; int bi = bestI[mi][i];
                #pragma unroll
                for (int s = 8; s; s >>= 1) {
                    float ov = __shfl_xor(bv, s, 16);
                    int   oi = __shfl_xor(bi, s, 16);
                    if (ov < bv || (ov == bv && oi < bi)) { bv = ov; bi = oi; }
                }
                bestV[mi][i] = bv; bestI[mi][i] = bi;
            }
        if (arow == 0) {
            #pragma unroll
            for (int mi = 0; mi < 2; ++mi)
                #pragma unroll
                for (int i = 0; i < 4; ++i) {
                    bV_sh[wv][mi * 16 + aq * 4 + i] = bestV[mi][i];
                    bI_sh[wv][mi * 16 + aq * 4 + i] = bestI[mi][i];
                }
        }
        __syncthreads();

        // ---- reduce across the 4 waves (codeword quarters), write index ----
        if (t < 32) {
            float bv = bV_sh[0][t]; int bi = bI_sh[0][t];
            #pragma unroll
            for (int q = 1; q < 4; ++q) {
                float ov = bV_sh[q][t]; int oi = bI_sh[q][t];
                if (ov < bv || (ov == bv && oi < bi)) { bv = ov; bi = oi; }
            }
            bidx_sh[t] = bi;
            out[NQ + (size_t)l * NROWS + row0 + t] = (float)bi;
        }
        __syncthreads();

        // ---- residual -= chosen codeword ----
        #pragma unroll
        for (int p = 0; p < 8; ++p) {
            int q = p * 256 + t;
            int row = q >> 6, fid = q & 63;
            const int bi = bidx_sh[row];
            const float4 w = *(const float4*)(W + (size_t)bi * DIM + fid * 4);
            float4 r = *(float4*)(&Rsh[row][fid * 4]);
            r.x -= w.x; r.y -= w.y; r.z -= w.z; r.w -= w.w;
            *(float4*)(&Rsh[row][fid * 4]) = r;
        }
        __syncthreads();
    }

    // ---- quantized_total = h - final residual ----
    #pragma unroll
    for (int p = 0; p < 8; ++p) {
        int q = p * 256 + t;
        int row = q >> 6, fid = q & 63;
        const float4 hv = *(const float4*)(h + (size_t)(row0 + row) * DIM + fid * 4);
        const float4 rv = *(const float4*)(&Rsh[row][fid * 4]);
        float4 o;
        o.x = hv.x - rv.x; o.y = hv.y - rv.y;
        o.z = hv.z - rv.z; o.w = hv.w - rv.w;
        *(float4*)(out + (size_t)(row0 + row) * DIM + fid * 4) = o;
    }
}

extern "C" void kernel_launch(void* const* d_in, const int* in_sizes, int n_in,
                              void* d_out, int out_size, void* d_ws, size_t ws_size,
                              hipStream_t stream) {
    const float* h  = (const float*)d_in[0];
    const float* cb = (const float*)d_in[1];
    float* out = (float*)d_out;
    unsigned short* F = (unsigned short*)d_ws;
    float* wsq = (float*)((char*)d_ws + F_BYTES);

    rvq_wsq   <<<dim3(24),   dim3(256), 0, stream>>>(cb, wsq);
    rvq_repack<<<dim3(3072), dim3(64),  0, stream>>>(cb, F);
    rvq_main  <<<dim3(NROWS / 32), dim3(256), 0, stream>>>(h, cb, F, wsq, out);
}

// Round 3
// 521.052 us; speedup vs baseline: 4.9040x; 1.0808x over previous
//
#include <hip/hip_runtime.h>
#include <math.h>

#define NUM_LAYERS 3
#define KCB 2048        // codebook size
#define DIM 256         // embed dim
#define NROWS 32768     // B*T
#define NQ (NROWS * DIM)
#define MROWS 64        // rows per block
#define RSTRIDE 260     // 256 + 4 pad

// d_ws layout:
//   F   : fp16 codebook fragments, [(layer*128+tn)*8+kb][hi|lo] blocks of 1024 B
//         element: lane*8 + j  ->  W[tn*16 + (lane&15)][kb*32 + (lane>>4)*8 + j]
//   wsq : fp32 ||w||^2 per codeword, 3*2048 floats, at byte offset F_BYTES
#define F_BYTES (3u * 128u * 8u * 2u * 1024u)   // 6,291,456

// dynamic LDS partition (bytes)
#define RSH_OFF  0              // 64*260*4 = 66560
#define WSQ_OFF  66560          // 2048*4   = 8192
#define RSQ_OFF  74752          // 64*4     = 256
#define BV_OFF   75008          // 4*64*4   = 1024
#define BI_OFF   76032          // 4*64*4   = 1024
#define BIDX_OFF 77056          // 64*4     = 256
#define SMEM_BYTES 77312

typedef _Float16 half8 __attribute__((ext_vector_type(8)));
typedef float   f32x4 __attribute__((ext_vector_type(4)));

// ---------------- prep: ||w||^2 ----------------
__global__ void rvq_wsq(const float* __restrict__ cb, float* __restrict__ wsq)
{
    int tid = blockIdx.x * 256 + threadIdx.x;   // 0 .. 6143
    const float* p = cb + (size_t)tid * DIM;
    float s = 0.f;
    #pragma unroll
    for (int u = 0; u < 64; ++u) {
        float4 v = *(const float4*)(p + u * 4);
        s = fmaf(v.x, v.x, s); s = fmaf(v.y, v.y, s);
        s = fmaf(v.z, v.z, s); s = fmaf(v.w, v.w, s);
    }
    wsq[tid] = s;
}

// ---------------- prep: fp16 hi/lo fragment repack ----------------
__global__ void rvq_repack(const float* __restrict__ cb, unsigned short* __restrict__ F)
{
    int b = blockIdx.x;
    int layer = b >> 10;
    int rem   = b & 1023;
    int tn    = rem >> 3;
    int kb    = rem & 7;
    int lane  = threadIdx.x;

    int cw = tn * 16 + (lane & 15);
    int k0 = kb * 32 + (lane >> 4) * 8;
    const float* src = cb + ((size_t)(layer * KCB + cw)) * DIM + k0;
    float4 x0 = *(const float4*)(src);
    float4 x1 = *(const float4*)(src + 4);
    float v[8] = {x0.x, x0.y, x0.z, x0.w, x1.x, x1.y, x1.z, x1.w};

    half8 hi, lo;
    #pragma unroll
    for (int j = 0; j < 8; ++j) {
        _Float16 h = (_Float16)v[j];
        hi[j] = h;
        lo[j] = (_Float16)(v[j] - (float)h);
    }
    size_t base = ((size_t)b) * 1024;   // ushort units
    *(half8*)(F + base + lane * 8)        = hi;
    *(half8*)(F + base + 512 + lane * 8)  = lo;
}

// ---------------- per-tile MFMA + argmin ----------------
__device__ __forceinline__ void mfma_tile(
    const half8 (&ahi)[4][8], const half8 (&alo)[4][8],
    const half8 (&bh)[8], const half8 (&bl)[8],
    const float (&rsq)[4][4], const float* wsq_sh,
    int colbase, int arow,
    float (&bestV)[4][4], int (&bestI)[4][4])
{
    f32x4 acc[4][2];
    const f32x4 z = {0.f, 0.f, 0.f, 0.f};
    #pragma unroll
    for (int mi = 0; mi < 4; ++mi) { acc[mi][0] = z; acc[mi][1] = z; }

    #pragma unroll
    for (int kb = 0; kb < 8; ++kb) {
        const int p = kb & 1;
        #pragma unroll
        for (int mi = 0; mi < 4; ++mi)
            acc[mi][p] = __builtin_amdgcn_mfma_f32_16x16x32_f16(ahi[mi][kb], bh[kb], acc[mi][p], 0, 0, 0);
        #pragma unroll
        for (int mi = 0; mi < 4; ++mi)
            acc[mi][p] = __builtin_amdgcn_mfma_f32_16x16x32_f16(alo[mi][kb], bh[kb], acc[mi][p], 0, 0, 0);
        #pragma unroll
        for (int mi = 0; mi < 4; ++mi)
            acc[mi][p] = __builtin_amdgcn_mfma_f32_16x16x32_f16(ahi[mi][kb], bl[kb], acc[mi][p], 0, 0, 0);
    }
    const int col = colbase + arow;
    const float wq = wsq_sh[col];
    #pragma unroll
    for (int mi = 0; mi < 4; ++mi)
        #pragma unroll
        for (int i = 0; i < 4; ++i) {
            float c = acc[mi][0][i] + acc[mi][1][i];
            float dist = (rsq[mi][i] - 2.f * c) + wq;
            if (dist < bestV[mi][i]) { bestV[mi][i] = dist; bestI[mi][i] = col; }
        }
}

// ---------------- main fused RVQ ----------------
__global__ __launch_bounds__(256, 1)
void rvq_main(const float* __restrict__ h,
              const float* __restrict__ cb,
              const unsigned short* __restrict__ F,
              const float* __restrict__ wsq,
              float* __restrict__ out)
{
    extern __shared__ char smem[];
    float* Rsh     = (float*)(smem + RSH_OFF);    // [64][RSTRIDE]
    float* wsq_sh  = (float*)(smem + WSQ_OFF);    // [2048]
    float* rsq_sh  = (float*)(smem + RSQ_OFF);    // [64]
    float* bV_sh   = (float*)(smem + BV_OFF);     // [4][64]
    int*   bI_sh   = (int*)  (smem + BI_OFF);     // [4][64]
    int*   bidx_sh = (int*)  (smem + BIDX_OFF);   // [64]

    const int t    = threadIdx.x;
    const int lane = t & 63;
    const int wv   = t >> 6;          // wave 0..3 -> codeword quarter
    const int row0 = blockIdx.x * MROWS;
    const int arow = lane & 15;       // fragment row / C col
    const int aq   = lane >> 4;       // fragment k-quad / C row-quad

    // ---- stage h tile ----
    #pragma unroll
    for (int p = 0; p < 16; ++p) {
        int q = p * 256 + t;
        int row = q >> 6, fid = q & 63;
        *(float4*)(&Rsh[row * RSTRIDE + fid * 4]) =
            *(const float4*)(h + (size_t)(row0 + row) * DIM + fid * 4);
    }
    __syncthreads();

    for (int l = 0; l < NUM_LAYERS; ++l) {
        const float* __restrict__ W = cb + (size_t)l * KCB * DIM;

        // ---- per-row ||r||^2 (4 lanes per row) + stage wsq to LDS ----
        {
            int row = t >> 2, g = t & 3;
            float s = 0.f;
            #pragma unroll
            for (int u = 0; u < 16; ++u) {
                float4 v = *(const float4*)(&Rsh[row * RSTRIDE + g * 64 + u * 4]);
                s = fmaf(v.x, v.x, s); s = fmaf(v.y, v.y, s);
                s = fmaf(v.z, v.z, s); s = fmaf(v.w, v.w, s);
            }
            s += __shfl_xor(s, 2, 4);
            s += __shfl_xor(s, 1, 4);
            if (g == 0) rsq_sh[row] = s;

            const float* wp = wsq + l * KCB + t * 8;
            *(float4*)(&wsq_sh[t * 8])     = *(const float4*)(wp);
            *(float4*)(&wsq_sh[t * 8 + 4]) = *(const float4*)(wp + 4);
        }
        __syncthreads();

        // ---- build A fragments (fp16 hi/lo) in registers (-> AGPRs) ----
        half8 ahi[4][8], alo[4][8];
        #pragma unroll
        for (int mi = 0; mi < 4; ++mi)
            #pragma unroll
            for (int kb = 0; kb < 8; ++kb) {
                const float* p = &Rsh[(mi * 16 + arow) * RSTRIDE + kb * 32 + aq * 8];
                float4 x0 = *(const float4*)(p);
                float4 x1 = *(const float4*)(p + 4);
                float v[8] = {x0.x, x0.y, x0.z, x0.w, x1.x, x1.y, x1.z, x1.w};
                #pragma unroll
                for (int j = 0; j < 8; ++j) {
                    _Float16 hv = (_Float16)v[j];
                    ahi[mi][kb][j] = hv;
                    alo[mi][kb][j] = (_Float16)(v[j] - (float)hv);
                }
            }

        float rsq[4][4];
        #pragma unroll
        for (int mi = 0; mi < 4; ++mi)
            #pragma unroll
            for (int i = 0; i < 4; ++i)
                rsq[mi][i] = rsq_sh[mi * 16 + aq * 4 + i];

        float bestV[4][4];
        int   bestI[4][4];
        #pragma unroll
        for (int mi = 0; mi < 4; ++mi)
            #pragma unroll
            for (int i = 0; i < 4; ++i) { bestV[mi][i] = INFINITY; bestI[mi][i] = 0; }

        const unsigned short* Fl = F + (size_t)l * 128 * 8192;

        // ---- nt loop: 32 N-tiles of 16 cw, double-buffered B prefetch ----
        half8 bh0[8], bl0[8], bh1[8], bl1[8];
        {
            const unsigned short* F0 = Fl + (size_t)(wv * 32) * 8192;
            #pragma unroll
            for (int kb = 0; kb < 8; ++kb) {
                bh0[kb] = *(const half8*)(F0 + kb * 1024 + lane * 8);
                bl0[kb] = *(const half8*)(F0 + kb * 1024 + 512 + lane * 8);
            }
        }
        for (int nt = 0; nt < 32; nt += 2) {
            const unsigned short* F1 = Fl + (size_t)(wv * 32 + nt + 1) * 8192;
            #pragma unroll
            for (int kb = 0; kb < 8; ++kb) {
                bh1[kb] = *(const half8*)(F1 + kb * 1024 + lane * 8);
                bl1[kb] = *(const half8*)(F1 + kb * 1024 + 512 + lane * 8);
            }
            mfma_tile(ahi, alo, bh0, bl0, rsq, wsq_sh,
                      wv * 512 + nt * 16, arow, bestV, bestI);
            if (nt + 2 < 32) {
                const unsigned short* F2 = Fl + (size_t)(wv * 32 + nt + 2) * 8192;
                #pragma unroll
                for (int kb = 0; kb < 8; ++kb) {
                    bh0[kb] = *(const half8*)(F2 + kb * 1024 + lane * 8);
                    bl0[kb] = *(const half8*)(F2 + kb * 1024 + 512 + lane * 8);
                }
            }
            mfma_tile(ahi, alo, bh1, bl1, rsq, wsq_sh,
                      wv * 512 + (nt + 1) * 16, arow, bestV, bestI);
        }

        // ---- reduce argmin across the 16 lanes sharing each row-quad ----
        #pragma unroll
        for (int mi = 0; mi < 4; ++mi)
            #pragma unroll
            for (int i = 0; i < 4; ++i) {
                float bv = bestV[mi][i]; int bi = bestI[mi][i];
                #pragma unroll
                for (int s = 8; s; s >>= 1) {
                    float ov = __shfl_xor(bv, s, 16);
                    int   oi = __shfl_xor(bi, s, 16);
                    if (ov < bv || (ov == bv && oi < bi)) { bv = ov; bi = oi; }
                }
                bestV[mi][i] = bv; bestI[mi][i] = bi;
            }
        if (arow == 0) {
            #pragma unroll
            for (int mi = 0; mi < 4; ++mi)
                #pragma unroll
                for (int i = 0; i < 4; ++i) {
                    bV_sh[wv * 64 + mi * 16 + aq * 4 + i] = bestV[mi][i];
                    bI_sh[wv * 64 + mi * 16 + aq * 4 + i] = bestI[mi][i];
                }
        }
        __syncthreads();

        // ---- reduce across the 4 waves (codeword quarters), write index ----
        if (t < 64) {
            float bv = bV_sh[t]; int bi = bI_sh[t];
            #pragma unroll
            for (int q = 1; q < 4; ++q) {
                float ov = bV_sh[q * 64 + t]; int oi = bI_sh[q * 64 + t];
                if (ov < bv || (ov == bv && oi < bi)) { bv = ov; bi = oi; }
            }
            bidx_sh[t] = bi;
            out[NQ + (size_t)l * NROWS + row0 + t] = (float)bi;
        }
        __syncthreads();

        // ---- residual -= chosen codeword (gather from L2) ----
        #pragma unroll
        for (int p = 0; p < 16; ++p) {
            int q = p * 256 + t;
            int row = q >> 6, fid = q & 63;
            const int bi = bidx_sh[row];
            const float4 w = *(const float4*)(W + (size_t)bi * DIM + fid * 4);
            float4 r = *(float4*)(&Rsh[row * RSTRIDE + fid * 4]);
            r.x -= w.x; r.y -= w.y; r.z -= w.z; r.w -= w.w;
            *(float4*)(&Rsh[row * RSTRIDE + fid * 4]) = r;
        }
        __syncthreads();
    }

    // ---- quantized_total = h - final residual ----
    #pragma unroll
    for (int p = 0; p < 16; ++p) {
        int q = p * 256 + t;
        int row = q >> 6, fid = q & 63;
        const float4 hv = *(const float4*)(h + (size_t)(row0 + row) * DIM + fid * 4);
        const float4 rv = *(const float4*)(&Rsh[row * RSTRIDE + fid * 4]);
        float4 o;
        o.x = hv.x - rv.x; o.y = hv.y - rv.y;
        o.z = hv.z - rv.z; o.w = hv.w - rv.w;
        *(float4*)(out + (size_t)(row0 + row) * DIM + fid * 4) = o;
    }
}

extern "C" void kernel_launch(void* const* d_in, const int* in_sizes, int n_in,
                              void* d_out, int out_size, void* d_ws, size_t ws_size,
                              hipStream_t stream) {
    const float* h  = (const float*)d_in[0];
    const float* cb = (const float*)d_in[1];
    float* out = (float*)d_out;
    unsigned short* F = (unsigned short*)d_ws;
    float* wsq = (float*)((char*)d_ws + F_BYTES);

    hipFuncSetAttribute((const void*)rvq_main,
                        hipFuncAttributeMaxDynamicSharedMemorySize, SMEM_BYTES);

    rvq_wsq   <<<dim3(24),   dim3(256), 0, stream>>>(cb, wsq);
    rvq_repack<<<dim3(3072), dim3(64),  0, stream>>>(cb, F);
    rvq_main  <<<dim3(NROWS / MROWS), dim3(256), SMEM_BYTES, stream>>>(h, cb, F, wsq, out);
}